// Round 3
// baseline (2634.328 us; speedup 1.0000x reference)
//
#include <hip/hip_runtime.h>

// Problem constants (fixed by setup_inputs)
#define NNODES 50000
#define NEDGES 800000
#define DIM    128
#define NRELS  4               // edge relations; weight slice 4 = self-loop
#define NB     (NRELS*NNODES)  // 200000 (rel,dst) bins
#define NBLKS  98              // scan blocks: 98*2048 = 200704 >= NB+1

typedef __attribute__((ext_vector_type(8))) short bf16x8;
typedef __attribute__((ext_vector_type(8))) unsigned short u16x8;
typedef __attribute__((ext_vector_type(4))) float f32x4;

// ---- ws layout (bytes); agg lives in d_out (k_node reads+writes in place) ----
#define SSRC_OFF   0            // u32[NEDGES+16]      3,200,064
#define CNT_OFF    3200256      // u32[200704]           802,816  (bins, then in-place excl scan)
#define BSUM_OFF   4003072      // u32[128]                  512
#define CTRL_OFF   4003584      // u32[64]: [0..3] grpcnt, [4..7] gcur, [8..12] gtoff
#define SSTART_OFF 4003840      // u32[204864]           819,456
#define SLEN_OFF   4823296      // u32[204864]           819,456
#define SDST_OFF   5642752      // i32[204864]           819,456
#define CUR_OFF    6462208      // u32[200064]           800,256
#define WT_OFF     7262464      // bf16[5*128*128]       163,840
#define XBF_OFF    7426304      // bf16[NNODES*DIM]   12,800,000  -> total 20,226,304

// monotonic float -> u32 key (order-preserving); key(any real) > 0, so 0 = "no edge"
__device__ __forceinline__ unsigned fkey(float f) {
  unsigned b = __float_as_uint(f);
  return (b & 0x80000000u) ? ~b : (b | 0x80000000u);
}
__device__ __forceinline__ float fval(unsigned k) {
  unsigned b = (k & 0x80000000u) ? (k ^ 0x80000000u) : ~k;
  return __uint_as_float(b);
}
__device__ __forceinline__ unsigned short f2bf(float f) {  // RNE f32->bf16
  unsigned u = __float_as_uint(f);
  return (unsigned short)((u + 0x7FFFu + ((u >> 16) & 1u)) >> 16);
}

// ---- init: zero agg (= d_out) and ws control/metadata region ----
__global__ void k_init(unsigned* __restrict__ agg, unsigned* __restrict__ z) {
  const int n1 = NNODES * DIM;
  const int n2 = (WT_OFF - CNT_OFF) / 4;
  int stride = gridDim.x * blockDim.x;
  int i0 = blockIdx.x * blockDim.x + threadIdx.x;
  for (int i = i0; i < n1; i += stride) agg[i] = 0u;
  for (int i = i0; i < n2; i += stride) z[i] = 0u;
}

// ---- convert x f32->bf16 (8/thread) and transpose+convert W: Wt[r][c][k]=W[r][k][c] ----
__global__ void k_convwt(const float* __restrict__ x, unsigned short* __restrict__ xbf,
                         const float* __restrict__ W, unsigned short* __restrict__ Wt) {
  int i = blockIdx.x * blockDim.x + threadIdx.x;
  if (i < NNODES * DIM / 8) {
    const float4* p = (const float4*)x + i * 2;
    float4 v0 = p[0], v1 = p[1];
    u16x8 o;
    o[0] = f2bf(v0.x); o[1] = f2bf(v0.y); o[2] = f2bf(v0.z); o[3] = f2bf(v0.w);
    o[4] = f2bf(v1.x); o[5] = f2bf(v1.y); o[6] = f2bf(v1.z); o[7] = f2bf(v1.w);
    *(u16x8*)(xbf + i * 8) = o;
  }
  if (i < 5 * DIM * DIM) {
    int r = i >> 14, rem = i & 16383, k = rem >> 7, c = rem & 127;
    Wt[(r << 14) + (c << 7) + k] = f2bf(W[i]);
  }
}

// ---- histogram over (rel,dst) bins ----
__global__ void k_hist(const int* __restrict__ rel, const int* __restrict__ dst,
                       unsigned* __restrict__ cnt) {
  int e = blockIdx.x * blockDim.x + threadIdx.x;
  if (e < NEDGES) {
    int r = rel[e]; r = r < 0 ? 0 : (r > NRELS - 1 ? NRELS - 1 : r);
    atomicAdd(&cnt[r * NNODES + dst[e]], 1u);
  }
}

// ---- block-local exclusive scan over cnt (2048/block), in place ----
__global__ void k_scanA(unsigned* __restrict__ cnt, unsigned* __restrict__ bsum) {
  __shared__ unsigned sh[256];
  int tid = threadIdx.x;
  int base = blockIdx.x * 2048 + tid * 8;
  unsigned v[8], tsum = 0;
#pragma unroll
  for (int j = 0; j < 8; j++) { v[j] = cnt[base + j]; tsum += v[j]; }
  sh[tid] = tsum;
  __syncthreads();
  for (int off = 1; off < 256; off <<= 1) {
    unsigned t = (tid >= off) ? sh[tid - off] : 0u;
    __syncthreads();
    sh[tid] += t;
    __syncthreads();
  }
  unsigned run = sh[tid] - tsum;  // exclusive prefix of this thread
#pragma unroll
  for (int j = 0; j < 8; j++) { unsigned t = v[j]; cnt[base + j] = run; run += t; }
  if (tid == 255) bsum[blockIdx.x] = sh[255];
}

// ---- add block-prefix (serial recompute of bsum prefix per block) ----
__global__ void k_scanC(unsigned* __restrict__ cnt, const unsigned* __restrict__ bsum) {
  int blk = blockIdx.x;
  if (blk == 0) return;
  unsigned p = 0;
  for (int k = 0; k < blk; k++) p += bsum[k];
  int base = blk * 2048 + threadIdx.x * 8;
#pragma unroll
  for (int j = 0; j < 8; j++) cnt[base + j] += p;
}

// ---- count non-empty groups per rel ----
__global__ void k_gcount(const unsigned* __restrict__ cnt, unsigned* __restrict__ ctrl) {
  __shared__ unsigned h[NRELS];
  if (threadIdx.x < NRELS) h[threadIdx.x] = 0u;
  __syncthreads();
  int b = blockIdx.x * blockDim.x + threadIdx.x;
  if (b < NB) {
    if (cnt[b + 1] > cnt[b]) atomicAdd(&h[b / NNODES], 1u);
  }
  __syncthreads();
  if (threadIdx.x < NRELS) atomicAdd(&ctrl[threadIdx.x], h[threadIdx.x]);
}

// ---- fill slot metadata (group -> slot within rel-tiled layout) + publish gtoff ----
__global__ void k_gfill(const unsigned* __restrict__ cnt, unsigned* __restrict__ ctrl,
                        unsigned* __restrict__ sstart, unsigned* __restrict__ slen,
                        int* __restrict__ sdst) {
  unsigned g0 = ctrl[0], g1 = ctrl[1], g2 = ctrl[2], g3 = ctrl[3];
  unsigned t1 = (g0 + 15) / 16;
  unsigned t2 = t1 + (g1 + 15) / 16;
  unsigned t3 = t2 + (g2 + 15) / 16;
  unsigned t4 = t3 + (g3 + 15) / 16;
  if (blockIdx.x == 0 && threadIdx.x == 0) {
    ctrl[8] = 0; ctrl[9] = t1; ctrl[10] = t2; ctrl[11] = t3; ctrl[12] = t4;
  }
  int b = blockIdx.x * blockDim.x + threadIdx.x;
  if (b < NB) {
    unsigned len = cnt[b + 1] - cnt[b];
    if (len) {
      int r = b / NNODES;
      unsigned loc = atomicAdd(&ctrl[4 + r], 1u);
      unsigned gt0 = (r == 0) ? 0u : (r == 1 ? t1 : (r == 2 ? t2 : t3));
      unsigned slot = gt0 * 16u + loc;
      sstart[slot] = cnt[b];
      slen[slot] = len;
      sdst[slot] = b - r * NNODES;
    }
  }
}

// ---- scatter src values into (rel,dst)-sorted edge order ----
__global__ void k_scat(const int* __restrict__ rel, const int* __restrict__ dst,
                       const int* __restrict__ src, const unsigned* __restrict__ cnt,
                       unsigned* __restrict__ cur, unsigned* __restrict__ ssrc) {
  int e = blockIdx.x * blockDim.x + threadIdx.x;
  if (e < NEDGES) {
    int r = rel[e]; r = r < 0 ? 0 : (r > NRELS - 1 ? NRELS - 1 : r);
    int key = r * NNODES + dst[e];
    unsigned pos = cnt[key] + atomicAdd(&cur[key], 1u);
    ssrc[pos] = (unsigned)src[e];
  }
}

// ---- group GEMM + per-group max + one atomicMax set per (rel,dst) group ----
// One wave per 16-group tile (rel-uniform). B (W^T) register-resident.
__global__ __launch_bounds__(256, 2) void k_edge(
    const unsigned short* __restrict__ xbf, const unsigned short* __restrict__ Wt,
    const float* __restrict__ bias, const unsigned* __restrict__ ssrc,
    const unsigned* __restrict__ sstart, const unsigned* __restrict__ slen,
    const int* __restrict__ sdst, const unsigned* __restrict__ ctrl,
    unsigned* __restrict__ agg) {
  int lane = threadIdx.x & 63;
  int wid = blockIdx.x * (blockDim.x >> 6) + (threadIdx.x >> 6);
  int nw = gridDim.x * (blockDim.x >> 6);
  int gt1 = (int)ctrl[9], gt2 = (int)ctrl[10], gt3 = (int)ctrl[11];
  int T = (int)ctrl[12];
  int tpw = (T + nw - 1) / nw;
  int t0 = wid * tpw, t1 = min(T, t0 + tpw);
  if (t0 >= t1) return;

  int col = lane & 15, quad = lane >> 4;
  bf16x8 B[8][4];
  float bs[8];
  int rcur = -1;

  for (int t = t0; t < t1; ++t) {
    int r = (t >= gt1) + (t >= gt2) + (t >= gt3);
    if (r != rcur) {
      rcur = r;
      const unsigned short* wr = Wt + (r << 14);
#pragma unroll
      for (int ct = 0; ct < 8; ct++) {
#pragma unroll
        for (int kk = 0; kk < 4; kk++)
          B[ct][kk] = *(const bf16x8*)(wr + ((ct * 16 + col) << 7) + kk * 32 + quad * 8);
        bs[ct] = bias[(r << 7) + ct * 16 + col];
      }
    }
    int sbase = t * 16;
    unsigned astart = sstart[sbase + col];   // this lane's A-row group
    int alen = (int)slen[sbase + col];
    int aclamp = alen > 0 ? alen - 1 : 0;
    int cdst[4], clen[4];                    // this lane's C-row groups (rows quad*4+j)
#pragma unroll
    for (int j = 0; j < 4; j++) {
      int sr = sbase + quad * 4 + j;
      cdst[j] = sdst[sr];
      clen[j] = (int)slen[sr];
    }
    f32x4 mx[8];
#pragma unroll
    for (int ct = 0; ct < 8; ct++) mx[ct] = (f32x4){-3.0e38f, -3.0e38f, -3.0e38f, -3.0e38f};

    int step = 0;
    unsigned sa = ssrc[astart];  // padding rows: alen=0, astart=0 -> valid dummy
    while (__any(step < alen)) {
      const unsigned short* xr = xbf + ((size_t)sa << 7);
      bf16x8 a0 = *(const bf16x8*)(xr + quad * 8);
      bf16x8 a1 = *(const bf16x8*)(xr + 32 + quad * 8);
      bf16x8 a2 = *(const bf16x8*)(xr + 64 + quad * 8);
      bf16x8 a3 = *(const bf16x8*)(xr + 96 + quad * 8);
      sa = ssrc[astart + min(step + 1, aclamp)];  // prefetch next step's src id
#pragma unroll
      for (int ct = 0; ct < 8; ct++) {
        f32x4 acc = {0.f, 0.f, 0.f, 0.f};
        acc = __builtin_amdgcn_mfma_f32_16x16x32_bf16(a0, B[ct][0], acc, 0, 0, 0);
        acc = __builtin_amdgcn_mfma_f32_16x16x32_bf16(a1, B[ct][1], acc, 0, 0, 0);
        acc = __builtin_amdgcn_mfma_f32_16x16x32_bf16(a2, B[ct][2], acc, 0, 0, 0);
        acc = __builtin_amdgcn_mfma_f32_16x16x32_bf16(a3, B[ct][3], acc, 0, 0, 0);
#pragma unroll
        for (int j = 0; j < 4; j++) mx[ct][j] = fmaxf(mx[ct][j], acc[j]);
      }
      step++;
    }
#pragma unroll
    for (int ct = 0; ct < 8; ct++) {
#pragma unroll
      for (int j = 0; j < 4; j++) {
        if (clen[j] > 0) {
          float v = mx[ct][j] + bs[ct];
          unsigned k = fkey(v);
          unsigned idx = ((unsigned)cdst[j] << 7) + (unsigned)(ct * 16 + col);
          if (agg[idx] < k) atomicMax(&agg[idx], k);  // stale read is <= actual: filter safe
        }
      }
    }
  }
}

// ---- self-loop GEMM + combine with decoded max-agg, in place in d_out ----
__global__ __launch_bounds__(256, 2) void k_node(
    const unsigned short* __restrict__ x, const unsigned short* __restrict__ Wt,
    const float* __restrict__ bias, unsigned* __restrict__ io) {
  int lane = threadIdx.x & 63;
  int wid = blockIdx.x * (blockDim.x >> 6) + (threadIdx.x >> 6);
  int col = lane & 15, quad = lane >> 4;
  int row0 = wid * 16;
  if (row0 >= NNODES) return;

  const unsigned short* wr = Wt + (4 << 14);
  bf16x8 B[8][4];
  float bs[8];
#pragma unroll
  for (int ct = 0; ct < 8; ct++) {
#pragma unroll
    for (int kk = 0; kk < 4; kk++)
      B[ct][kk] = *(const bf16x8*)(wr + ((ct * 16 + col) << 7) + kk * 32 + quad * 8);
    bs[ct] = bias[(4 << 7) + ct * 16 + col];
  }
  int na = min(row0 + col, NNODES - 1);
  bf16x8 a0 = *(const bf16x8*)(x + (na << 7) + quad * 8);
  bf16x8 a1 = *(const bf16x8*)(x + (na << 7) + 32 + quad * 8);
  bf16x8 a2 = *(const bf16x8*)(x + (na << 7) + 64 + quad * 8);
  bf16x8 a3 = *(const bf16x8*)(x + (na << 7) + 96 + quad * 8);

#pragma unroll
  for (int ct = 0; ct < 8; ct++) {
    f32x4 acc = {0.f, 0.f, 0.f, 0.f};
    acc = __builtin_amdgcn_mfma_f32_16x16x32_bf16(a0, B[ct][0], acc, 0, 0, 0);
    acc = __builtin_amdgcn_mfma_f32_16x16x32_bf16(a1, B[ct][1], acc, 0, 0, 0);
    acc = __builtin_amdgcn_mfma_f32_16x16x32_bf16(a2, B[ct][2], acc, 0, 0, 0);
    acc = __builtin_amdgcn_mfma_f32_16x16x32_bf16(a3, B[ct][3], acc, 0, 0, 0);
#pragma unroll
    for (int j = 0; j < 4; j++) {
      int n = row0 + quad * 4 + j;
      if (n < NNODES) {
        unsigned idx = ((unsigned)n << 7) + (unsigned)(ct * 16 + col);
        unsigned k = io[idx];
        float av = (k == 0u) ? 0.f : fval(k);
        io[idx] = __float_as_uint(acc[j] + bs[ct] + av);
      }
    }
  }
}

extern "C" void kernel_launch(void* const* d_in, const int* in_sizes, int n_in,
                              void* d_out, int out_size, void* d_ws, size_t ws_size,
                              hipStream_t stream) {
  const float* x = (const float*)d_in[0];
  const float* W = (const float*)d_in[1];
  const float* bias = (const float*)d_in[2];
  const int* src = (const int*)d_in[3];
  const int* dst = (const int*)d_in[4];
  const int* rel = (const int*)d_in[5];

  char* ws = (char*)d_ws;
  unsigned* ssrc = (unsigned*)(ws + SSRC_OFF);
  unsigned* cnt = (unsigned*)(ws + CNT_OFF);
  unsigned* bsum = (unsigned*)(ws + BSUM_OFF);
  unsigned* ctrl = (unsigned*)(ws + CTRL_OFF);
  unsigned* sstart = (unsigned*)(ws + SSTART_OFF);
  unsigned* slen = (unsigned*)(ws + SLEN_OFF);
  int* sdst = (int*)(ws + SDST_OFF);
  unsigned* cur = (unsigned*)(ws + CUR_OFF);
  unsigned short* Wt = (unsigned short*)(ws + WT_OFF);
  unsigned short* xbf = (unsigned short*)(ws + XBF_OFF);
  unsigned* agg = (unsigned*)d_out;  // agg keys live in d_out; k_node finalizes in place

  hipLaunchKernelGGL(k_init, dim3(2048), dim3(256), 0, stream, agg, cnt);
  hipLaunchKernelGGL(k_convwt, dim3(3125), dim3(256), 0, stream, x, xbf, W, Wt);
  hipLaunchKernelGGL(k_hist, dim3(3125), dim3(256), 0, stream, rel, dst, cnt);
  hipLaunchKernelGGL(k_scanA, dim3(NBLKS), dim3(256), 0, stream, cnt, bsum);
  hipLaunchKernelGGL(k_scanC, dim3(NBLKS), dim3(256), 0, stream, cnt, bsum);
  hipLaunchKernelGGL(k_gcount, dim3(782), dim3(256), 0, stream, cnt, ctrl);
  hipLaunchKernelGGL(k_gfill, dim3(782), dim3(256), 0, stream, cnt, ctrl, sstart, slen, sdst);
  hipLaunchKernelGGL(k_scat, dim3(3125), dim3(256), 0, stream, rel, dst, src, cnt, cur, ssrc);
  hipLaunchKernelGGL(k_edge, dim3(1024), dim3(256), 0, stream, xbf, Wt, bias, ssrc, sstart, slen,
                     sdst, ctrl, agg);
  hipLaunchKernelGGL(k_node, dim3(782), dim3(256), 0, stream, xbf, Wt, bias, agg);
}

// Round 4
// 412.807 us; speedup vs baseline: 6.3815x; 6.3815x over previous
//
#include <hip/hip_runtime.h>

// Problem constants (fixed by setup_inputs)
#define NNODES 50000
#define NEDGES 800000
#define DIM    128
#define NRELS  4               // edge relations; weight slice 4 = self-loop
#define NB     (NRELS*NNODES)  // 200000 (rel,dst) bins
#define NBLKS  98              // scan blocks: 98*2048 = 200704 >= NB+1

typedef __attribute__((ext_vector_type(8))) short bf16x8;
typedef __attribute__((ext_vector_type(8))) unsigned short u16x8;
typedef __attribute__((ext_vector_type(4))) float f32x4;

// ---- ws layout (bytes); agg lives in d_out (k_node reads+writes in place) ----
#define SSRC_OFF   0            // u32[NEDGES+16]      3,200,064
#define CNT_OFF    3200256      // u32[200704]           802,816  (bins, then in-place excl scan)
#define BSUM_OFF   4003072      // u32[128]                  512
#define CTRL_OFF   4003584      // u32[64]: [0..3] grpcnt, [4..7] gcur, [8..12] gtoff
#define SSTART_OFF 4003840      // u32[204864]           819,456
#define SLEN_OFF   4823296      // u32[204864]           819,456
#define SDST_OFF   5642752      // i32[204864]           819,456
#define CUR_OFF    6462208      // u32[200064]           800,256
#define WT_OFF     7262464      // bf16[5*128*128]       163,840
#define XBF_OFF    7426304      // bf16[NNODES*DIM]   12,800,000  -> total 20,226,304

// monotonic float -> u32 key (order-preserving); key(any real) > 0, so 0 = "no edge"
__device__ __forceinline__ unsigned fkey(float f) {
  unsigned b = __float_as_uint(f);
  return (b & 0x80000000u) ? ~b : (b | 0x80000000u);
}
__device__ __forceinline__ float fval(unsigned k) {
  unsigned b = (k & 0x80000000u) ? (k ^ 0x80000000u) : ~k;
  return __uint_as_float(b);
}
__device__ __forceinline__ unsigned short f2bf(float f) {  // RNE f32->bf16
  unsigned u = __float_as_uint(f);
  return (unsigned short)((u + 0x7FFFu + ((u >> 16) & 1u)) >> 16);
}

// ---- init: zero agg (= d_out) and ws control/metadata region ----
__global__ void k_init(unsigned* __restrict__ agg, unsigned* __restrict__ z) {
  const int n1 = NNODES * DIM;
  const int n2 = (WT_OFF - CNT_OFF) / 4;
  int stride = gridDim.x * blockDim.x;
  int i0 = blockIdx.x * blockDim.x + threadIdx.x;
  for (int i = i0; i < n1; i += stride) agg[i] = 0u;
  for (int i = i0; i < n2; i += stride) z[i] = 0u;
}

// ---- convert x f32->bf16 (8/thread) and transpose+convert W: Wt[r][c][k]=W[r][k][c] ----
__global__ void k_convwt(const float* __restrict__ x, unsigned short* __restrict__ xbf,
                         const float* __restrict__ W, unsigned short* __restrict__ Wt) {
  int i = blockIdx.x * blockDim.x + threadIdx.x;
  if (i < NNODES * DIM / 8) {
    const float4* p = (const float4*)x + i * 2;
    float4 v0 = p[0], v1 = p[1];
    u16x8 o;
    o[0] = f2bf(v0.x); o[1] = f2bf(v0.y); o[2] = f2bf(v0.z); o[3] = f2bf(v0.w);
    o[4] = f2bf(v1.x); o[5] = f2bf(v1.y); o[6] = f2bf(v1.z); o[7] = f2bf(v1.w);
    *(u16x8*)(xbf + i * 8) = o;
  }
  if (i < 5 * DIM * DIM) {
    int r = i >> 14, rem = i & 16383, k = rem >> 7, c = rem & 127;
    Wt[(r << 14) + (c << 7) + k] = f2bf(W[i]);
  }
}

// ---- histogram over (rel,dst) bins ----
__global__ void k_hist(const int* __restrict__ rel, const int* __restrict__ dst,
                       unsigned* __restrict__ cnt) {
  int e = blockIdx.x * blockDim.x + threadIdx.x;
  if (e < NEDGES) {
    int r = rel[e]; r = r < 0 ? 0 : (r > NRELS - 1 ? NRELS - 1 : r);
    atomicAdd(&cnt[r * NNODES + dst[e]], 1u);
  }
}

// ---- block-local exclusive scan over cnt (2048/block), in place ----
__global__ void k_scanA(unsigned* __restrict__ cnt, unsigned* __restrict__ bsum) {
  __shared__ unsigned sh[256];
  int tid = threadIdx.x;
  int base = blockIdx.x * 2048 + tid * 8;
  unsigned v[8], tsum = 0;
#pragma unroll
  for (int j = 0; j < 8; j++) { v[j] = cnt[base + j]; tsum += v[j]; }
  sh[tid] = tsum;
  __syncthreads();
  for (int off = 1; off < 256; off <<= 1) {
    unsigned t = (tid >= off) ? sh[tid - off] : 0u;
    __syncthreads();
    sh[tid] += t;
    __syncthreads();
  }
  unsigned run = sh[tid] - tsum;  // exclusive prefix of this thread
#pragma unroll
  for (int j = 0; j < 8; j++) { unsigned t = v[j]; cnt[base + j] = run; run += t; }
  if (tid == 255) bsum[blockIdx.x] = sh[255];
}

// ---- add block-prefix (serial recompute of bsum prefix per block) ----
__global__ void k_scanC(unsigned* __restrict__ cnt, const unsigned* __restrict__ bsum) {
  int blk = blockIdx.x;
  if (blk == 0) return;
  unsigned p = 0;
  for (int k = 0; k < blk; k++) p += bsum[k];
  int base = blk * 2048 + threadIdx.x * 8;
#pragma unroll
  for (int j = 0; j < 8; j++) cnt[base + j] += p;
}

// ---- count non-empty groups per rel (LDS-aggregated) ----
__global__ void k_gcount(const unsigned* __restrict__ cnt, unsigned* __restrict__ ctrl) {
  __shared__ unsigned h[NRELS];
  if (threadIdx.x < NRELS) h[threadIdx.x] = 0u;
  __syncthreads();
  int b = blockIdx.x * blockDim.x + threadIdx.x;
  if (b < NB) {
    if (cnt[b + 1] > cnt[b]) atomicAdd(&h[b / NNODES], 1u);
  }
  __syncthreads();
  if (threadIdx.x < NRELS) atomicAdd(&ctrl[threadIdx.x], h[threadIdx.x]);
}

// ---- fill slot metadata (group -> slot within rel-tiled layout) + publish gtoff ----
// LDS-local rank + ONE global atomicAdd per (block,rel): slot order within a rel is
// arbitrary, only uniqueness matters. (Per-thread global atomics to ctrl[4+r] serialized
// at 4 addresses and cost 2.2 ms in round 3.)
__global__ void k_gfill(const unsigned* __restrict__ cnt, unsigned* __restrict__ ctrl,
                        unsigned* __restrict__ sstart, unsigned* __restrict__ slen,
                        int* __restrict__ sdst) {
  __shared__ unsigned h[NRELS];
  __shared__ unsigned base[NRELS];
  unsigned g0 = ctrl[0], g1 = ctrl[1], g2 = ctrl[2], g3 = ctrl[3];
  unsigned t1 = (g0 + 15) / 16;
  unsigned t2 = t1 + (g1 + 15) / 16;
  unsigned t3 = t2 + (g2 + 15) / 16;
  unsigned t4 = t3 + (g3 + 15) / 16;
  if (blockIdx.x == 0 && threadIdx.x == 0) {
    ctrl[8] = 0; ctrl[9] = t1; ctrl[10] = t2; ctrl[11] = t3; ctrl[12] = t4;
  }
  if (threadIdx.x < NRELS) h[threadIdx.x] = 0u;
  __syncthreads();
  int b = blockIdx.x * blockDim.x + threadIdx.x;
  int r = 0;
  unsigned len = 0, loc = 0, start = 0;
  if (b < NB) {
    start = cnt[b];
    len = cnt[b + 1] - start;
    if (len) {
      r = b / NNODES;
      loc = atomicAdd(&h[r], 1u);
    }
  }
  __syncthreads();
  if (threadIdx.x < NRELS) base[threadIdx.x] = atomicAdd(&ctrl[4 + threadIdx.x], h[threadIdx.x]);
  __syncthreads();
  if (len) {
    unsigned gt0 = (r == 0) ? 0u : (r == 1 ? t1 : (r == 2 ? t2 : t3));
    unsigned slot = gt0 * 16u + base[r] + loc;
    sstart[slot] = start;
    slen[slot] = len;
    sdst[slot] = b - r * NNODES;
  }
}

// ---- scatter src values into (rel,dst)-sorted edge order ----
__global__ void k_scat(const int* __restrict__ rel, const int* __restrict__ dst,
                       const int* __restrict__ src, const unsigned* __restrict__ cnt,
                       unsigned* __restrict__ cur, unsigned* __restrict__ ssrc) {
  int e = blockIdx.x * blockDim.x + threadIdx.x;
  if (e < NEDGES) {
    int r = rel[e]; r = r < 0 ? 0 : (r > NRELS - 1 ? NRELS - 1 : r);
    int key = r * NNODES + dst[e];
    unsigned pos = cnt[key] + atomicAdd(&cur[key], 1u);
    ssrc[pos] = (unsigned)src[e];
  }
}

// ---- group GEMM + per-group max + one atomicMax set per (rel,dst) group ----
// One wave per 16-group tile (rel-uniform). B (W^T) register-resident.
__global__ __launch_bounds__(256, 2) void k_edge(
    const unsigned short* __restrict__ xbf, const unsigned short* __restrict__ Wt,
    const float* __restrict__ bias, const unsigned* __restrict__ ssrc,
    const unsigned* __restrict__ sstart, const unsigned* __restrict__ slen,
    const int* __restrict__ sdst, const unsigned* __restrict__ ctrl,
    unsigned* __restrict__ agg) {
  int lane = threadIdx.x & 63;
  int wid = blockIdx.x * (blockDim.x >> 6) + (threadIdx.x >> 6);
  int nw = gridDim.x * (blockDim.x >> 6);
  int gt1 = (int)ctrl[9], gt2 = (int)ctrl[10], gt3 = (int)ctrl[11];
  int T = (int)ctrl[12];
  int tpw = (T + nw - 1) / nw;
  int t0 = wid * tpw, t1 = min(T, t0 + tpw);
  if (t0 >= t1) return;

  int col = lane & 15, quad = lane >> 4;
  bf16x8 B[8][4];
  float bs[8];
  int rcur = -1;

  for (int t = t0; t < t1; ++t) {
    int r = (t >= gt1) + (t >= gt2) + (t >= gt3);
    if (r != rcur) {
      rcur = r;
      const unsigned short* wr = Wt + (r << 14);
#pragma unroll
      for (int ct = 0; ct < 8; ct++) {
#pragma unroll
        for (int kk = 0; kk < 4; kk++)
          B[ct][kk] = *(const bf16x8*)(wr + ((ct * 16 + col) << 7) + kk * 32 + quad * 8);
        bs[ct] = bias[(r << 7) + ct * 16 + col];
      }
    }
    int sbase = t * 16;
    unsigned astart = sstart[sbase + col];   // this lane's A-row group
    int alen = (int)slen[sbase + col];
    int aclamp = alen > 0 ? alen - 1 : 0;
    int cdst[4], clen[4];                    // this lane's C-row groups (rows quad*4+j)
#pragma unroll
    for (int j = 0; j < 4; j++) {
      int sr = sbase + quad * 4 + j;
      cdst[j] = sdst[sr];
      clen[j] = (int)slen[sr];
    }
    f32x4 mx[8];
#pragma unroll
    for (int ct = 0; ct < 8; ct++) mx[ct] = (f32x4){-3.0e38f, -3.0e38f, -3.0e38f, -3.0e38f};

    int step = 0;
    unsigned sa = ssrc[astart];  // padding rows: alen=0, astart=0 -> valid dummy
    while (__any(step < alen)) {
      const unsigned short* xr = xbf + ((size_t)sa << 7);
      bf16x8 a0 = *(const bf16x8*)(xr + quad * 8);
      bf16x8 a1 = *(const bf16x8*)(xr + 32 + quad * 8);
      bf16x8 a2 = *(const bf16x8*)(xr + 64 + quad * 8);
      bf16x8 a3 = *(const bf16x8*)(xr + 96 + quad * 8);
      sa = ssrc[astart + min(step + 1, aclamp)];  // prefetch next step's src id
#pragma unroll
      for (int ct = 0; ct < 8; ct++) {
        f32x4 acc = {0.f, 0.f, 0.f, 0.f};
        acc = __builtin_amdgcn_mfma_f32_16x16x32_bf16(a0, B[ct][0], acc, 0, 0, 0);
        acc = __builtin_amdgcn_mfma_f32_16x16x32_bf16(a1, B[ct][1], acc, 0, 0, 0);
        acc = __builtin_amdgcn_mfma_f32_16x16x32_bf16(a2, B[ct][2], acc, 0, 0, 0);
        acc = __builtin_amdgcn_mfma_f32_16x16x32_bf16(a3, B[ct][3], acc, 0, 0, 0);
#pragma unroll
        for (int j = 0; j < 4; j++) mx[ct][j] = fmaxf(mx[ct][j], acc[j]);
      }
      step++;
    }
#pragma unroll
    for (int ct = 0; ct < 8; ct++) {
#pragma unroll
      for (int j = 0; j < 4; j++) {
        if (clen[j] > 0) {
          float v = mx[ct][j] + bs[ct];
          unsigned k = fkey(v);
          unsigned idx = ((unsigned)cdst[j] << 7) + (unsigned)(ct * 16 + col);
          if (agg[idx] < k) atomicMax(&agg[idx], k);  // stale read is <= actual: filter safe
        }
      }
    }
  }
}

// ---- self-loop GEMM + combine with decoded max-agg, in place in d_out ----
__global__ __launch_bounds__(256, 2) void k_node(
    const unsigned short* __restrict__ x, const unsigned short* __restrict__ Wt,
    const float* __restrict__ bias, unsigned* __restrict__ io) {
  int lane = threadIdx.x & 63;
  int wid = blockIdx.x * (blockDim.x >> 6) + (threadIdx.x >> 6);
  int col = lane & 15, quad = lane >> 4;
  int row0 = wid * 16;
  if (row0 >= NNODES) return;

  const unsigned short* wr = Wt + (4 << 14);
  bf16x8 B[8][4];
  float bs[8];
#pragma unroll
  for (int ct = 0; ct < 8; ct++) {
#pragma unroll
    for (int kk = 0; kk < 4; kk++)
      B[ct][kk] = *(const bf16x8*)(wr + ((ct * 16 + col) << 7) + kk * 32 + quad * 8);
    bs[ct] = bias[(4 << 7) + ct * 16 + col];
  }
  int na = min(row0 + col, NNODES - 1);
  bf16x8 a0 = *(const bf16x8*)(x + (na << 7) + quad * 8);
  bf16x8 a1 = *(const bf16x8*)(x + (na << 7) + 32 + quad * 8);
  bf16x8 a2 = *(const bf16x8*)(x + (na << 7) + 64 + quad * 8);
  bf16x8 a3 = *(const bf16x8*)(x + (na << 7) + 96 + quad * 8);

#pragma unroll
  for (int ct = 0; ct < 8; ct++) {
    f32x4 acc = {0.f, 0.f, 0.f, 0.f};
    acc = __builtin_amdgcn_mfma_f32_16x16x32_bf16(a0, B[ct][0], acc, 0, 0, 0);
    acc = __builtin_amdgcn_mfma_f32_16x16x32_bf16(a1, B[ct][1], acc, 0, 0, 0);
    acc = __builtin_amdgcn_mfma_f32_16x16x32_bf16(a2, B[ct][2], acc, 0, 0, 0);
    acc = __builtin_amdgcn_mfma_f32_16x16x32_bf16(a3, B[ct][3], acc, 0, 0, 0);
#pragma unroll
    for (int j = 0; j < 4; j++) {
      int n = row0 + quad * 4 + j;
      if (n < NNODES) {
        unsigned idx = ((unsigned)n << 7) + (unsigned)(ct * 16 + col);
        unsigned k = io[idx];
        float av = (k == 0u) ? 0.f : fval(k);
        io[idx] = __float_as_uint(acc[j] + bs[ct] + av);
      }
    }
  }
}

extern "C" void kernel_launch(void* const* d_in, const int* in_sizes, int n_in,
                              void* d_out, int out_size, void* d_ws, size_t ws_size,
                              hipStream_t stream) {
  const float* x = (const float*)d_in[0];
  const float* W = (const float*)d_in[1];
  const float* bias = (const float*)d_in[2];
  const int* src = (const int*)d_in[3];
  const int* dst = (const int*)d_in[4];
  const int* rel = (const int*)d_in[5];

  char* ws = (char*)d_ws;
  unsigned* ssrc = (unsigned*)(ws + SSRC_OFF);
  unsigned* cnt = (unsigned*)(ws + CNT_OFF);
  unsigned* bsum = (unsigned*)(ws + BSUM_OFF);
  unsigned* ctrl = (unsigned*)(ws + CTRL_OFF);
  unsigned* sstart = (unsigned*)(ws + SSTART_OFF);
  unsigned* slen = (unsigned*)(ws + SLEN_OFF);
  int* sdst = (int*)(ws + SDST_OFF);
  unsigned* cur = (unsigned*)(ws + CUR_OFF);
  unsigned short* Wt = (unsigned short*)(ws + WT_OFF);
  unsigned short* xbf = (unsigned short*)(ws + XBF_OFF);
  unsigned* agg = (unsigned*)d_out;  // agg keys live in d_out; k_node finalizes in place

  hipLaunchKernelGGL(k_init, dim3(2048), dim3(256), 0, stream, agg, cnt);
  hipLaunchKernelGGL(k_convwt, dim3(3125), dim3(256), 0, stream, x, xbf, W, Wt);
  hipLaunchKernelGGL(k_hist, dim3(3125), dim3(256), 0, stream, rel, dst, cnt);
  hipLaunchKernelGGL(k_scanA, dim3(NBLKS), dim3(256), 0, stream, cnt, bsum);
  hipLaunchKernelGGL(k_scanC, dim3(NBLKS), dim3(256), 0, stream, cnt, bsum);
  hipLaunchKernelGGL(k_gcount, dim3(782), dim3(256), 0, stream, cnt, ctrl);
  hipLaunchKernelGGL(k_gfill, dim3(782), dim3(256), 0, stream, cnt, ctrl, sstart, slen, sdst);
  hipLaunchKernelGGL(k_scat, dim3(3125), dim3(256), 0, stream, rel, dst, src, cnt, cur, ssrc);
  hipLaunchKernelGGL(k_edge, dim3(1024), dim3(256), 0, stream, xbf, Wt, bias, ssrc, sstart, slen,
                     sdst, ctrl, agg);
  hipLaunchKernelGGL(k_node, dim3(782), dim3(256), 0, stream, xbf, Wt, bias, agg);
}

// Round 5
// 384.326 us; speedup vs baseline: 6.8544x; 1.0741x over previous
//
#include <hip/hip_runtime.h>

// Problem constants (fixed by setup_inputs)
#define NNODES 50000
#define NEDGES 800000
#define DIM    128
#define NRELS  4               // edge relations; weight slice 4 = self-loop
#define NB     (NRELS*NNODES)  // 200000 (rel,dst) bins
#define NBLKS  98              // scan blocks: 98*2048 = 200704 >= NB+1
#define NSLOTS 200128          // max slots incl per-rel tile padding

typedef __attribute__((ext_vector_type(8))) short bf16x8;
typedef __attribute__((ext_vector_type(8))) unsigned short u16x8;
typedef __attribute__((ext_vector_type(4))) float f32x4;

// ---- ws layout (bytes) ----
#define SSRC_OFF   0            // u32[NEDGES+16]        3,200,064
#define CNT_OFF    3200256      // u32[200704]             802,816 (bins -> excl scan)
#define BSUM_OFF   4003072      // u32[128]
#define CTRL_OFF   4003584      // u32[64]: [0..3] grpcnt, [4..7] gcur, [8..12] tile offs
#define SSTART_OFF 4003840      // u32[NSLOTS]             800,512
#define SLEN_OFF   4804352      // u32[NSLOTS]             800,512
#define CUR_OFF    5604864      // u32[NB]                 800,256
#define SLOTOF_OFF 6405120      // u32[NB] (0xFFFFFFFF = empty)  800,256
#define WT_OFF     7205376      // bf16[5*128*128]         163,840
#define XBF_OFF    7369216      // bf16[NNODES*DIM]     12,800,000
#define GMAX_OFF   20169216     // bf16[NSLOTS*128]     51,232,768 -> total ~71.4 MB

__device__ __forceinline__ unsigned short f2bf(float f) {  // RNE f32->bf16
  unsigned u = __float_as_uint(f);
  return (unsigned short)((u + 0x7FFFu + ((u >> 16) & 1u)) >> 16);
}
__device__ __forceinline__ float bf2f(unsigned short u) {
  return __uint_as_float(((unsigned)u) << 16);
}

// ---- init: zero cnt/ctrl/sstart/slen/cur; slotof = 0xFFFFFFFF ----
__global__ void k_init(unsigned* __restrict__ z, unsigned* __restrict__ sf) {
  const int nz = (SLOTOF_OFF - CNT_OFF) / 4;   // 801,216
  const int nf = (WT_OFF - SLOTOF_OFF) / 4;    // 200,064
  int stride = gridDim.x * blockDim.x;
  int i0 = blockIdx.x * blockDim.x + threadIdx.x;
  for (int i = i0; i < nz; i += stride) z[i] = 0u;
  for (int i = i0; i < nf; i += stride) sf[i] = 0xFFFFFFFFu;
}

// ---- convert x f32->bf16 (8/thread) and transpose+convert W: Wt[r][c][k]=W[r][k][c] ----
__global__ void k_convwt(const float* __restrict__ x, unsigned short* __restrict__ xbf,
                         const float* __restrict__ W, unsigned short* __restrict__ Wt) {
  int i = blockIdx.x * blockDim.x + threadIdx.x;
  if (i < NNODES * DIM / 8) {
    const float4* p = (const float4*)x + i * 2;
    float4 v0 = p[0], v1 = p[1];
    u16x8 o;
    o[0] = f2bf(v0.x); o[1] = f2bf(v0.y); o[2] = f2bf(v0.z); o[3] = f2bf(v0.w);
    o[4] = f2bf(v1.x); o[5] = f2bf(v1.y); o[6] = f2bf(v1.z); o[7] = f2bf(v1.w);
    *(u16x8*)(xbf + i * 8) = o;
  }
  if (i < 5 * DIM * DIM) {
    int r = i >> 14, rem = i & 16383, k = rem >> 7, c = rem & 127;
    Wt[(r << 14) + (c << 7) + k] = f2bf(W[i]);
  }
}

// ---- histogram over (rel,dst) bins ----
__global__ void k_hist(const int* __restrict__ rel, const int* __restrict__ dst,
                       unsigned* __restrict__ cnt) {
  int e = blockIdx.x * blockDim.x + threadIdx.x;
  if (e < NEDGES) {
    int r = rel[e]; r = r < 0 ? 0 : (r > NRELS - 1 ? NRELS - 1 : r);
    atomicAdd(&cnt[r * NNODES + dst[e]], 1u);
  }
}

// ---- block-local exclusive scan over cnt (2048/block), in place ----
__global__ void k_scanA(unsigned* __restrict__ cnt, unsigned* __restrict__ bsum) {
  __shared__ unsigned sh[256];
  int tid = threadIdx.x;
  int base = blockIdx.x * 2048 + tid * 8;
  unsigned v[8], tsum = 0;
#pragma unroll
  for (int j = 0; j < 8; j++) { v[j] = cnt[base + j]; tsum += v[j]; }
  sh[tid] = tsum;
  __syncthreads();
  for (int off = 1; off < 256; off <<= 1) {
    unsigned t = (tid >= off) ? sh[tid - off] : 0u;
    __syncthreads();
    sh[tid] += t;
    __syncthreads();
  }
  unsigned run = sh[tid] - tsum;
#pragma unroll
  for (int j = 0; j < 8; j++) { unsigned t = v[j]; cnt[base + j] = run; run += t; }
  if (tid == 255) bsum[blockIdx.x] = sh[255];
}

// ---- add block-prefix ----
__global__ void k_scanC(unsigned* __restrict__ cnt, const unsigned* __restrict__ bsum) {
  int blk = blockIdx.x;
  if (blk == 0) return;
  unsigned p = 0;
  for (int k = 0; k < blk; k++) p += bsum[k];
  int base = blk * 2048 + threadIdx.x * 8;
#pragma unroll
  for (int j = 0; j < 8; j++) cnt[base + j] += p;
}

// ---- count non-empty groups per rel (LDS-aggregated) ----
__global__ void k_gcount(const unsigned* __restrict__ cnt, unsigned* __restrict__ ctrl) {
  __shared__ unsigned h[NRELS];
  if (threadIdx.x < NRELS) h[threadIdx.x] = 0u;
  __syncthreads();
  int b = blockIdx.x * blockDim.x + threadIdx.x;
  if (b < NB) {
    if (cnt[b + 1] > cnt[b]) atomicAdd(&h[b / NNODES], 1u);
  }
  __syncthreads();
  if (threadIdx.x < NRELS) atomicAdd(&ctrl[threadIdx.x], h[threadIdx.x]);
}

// ---- fill slot metadata + slotof lookup (LDS-ranked; 1 global atomic per block,rel) ----
__global__ void k_gfill(const unsigned* __restrict__ cnt, unsigned* __restrict__ ctrl,
                        unsigned* __restrict__ sstart, unsigned* __restrict__ slen,
                        unsigned* __restrict__ slotof) {
  __shared__ unsigned h[NRELS];
  __shared__ unsigned base[NRELS];
  unsigned g0 = ctrl[0], g1 = ctrl[1], g2 = ctrl[2], g3 = ctrl[3];
  unsigned t1 = (g0 + 15) / 16;
  unsigned t2 = t1 + (g1 + 15) / 16;
  unsigned t3 = t2 + (g2 + 15) / 16;
  unsigned t4 = t3 + (g3 + 15) / 16;
  if (blockIdx.x == 0 && threadIdx.x == 0) {
    ctrl[8] = 0; ctrl[9] = t1; ctrl[10] = t2; ctrl[11] = t3; ctrl[12] = t4;
  }
  if (threadIdx.x < NRELS) h[threadIdx.x] = 0u;
  __syncthreads();
  int b = blockIdx.x * blockDim.x + threadIdx.x;
  int r = 0;
  unsigned len = 0, loc = 0, start = 0;
  if (b < NB) {
    start = cnt[b];
    len = cnt[b + 1] - start;
    if (len) {
      r = b / NNODES;
      loc = atomicAdd(&h[r], 1u);
    }
  }
  __syncthreads();
  if (threadIdx.x < NRELS) base[threadIdx.x] = atomicAdd(&ctrl[4 + threadIdx.x], h[threadIdx.x]);
  __syncthreads();
  if (len) {
    unsigned gt0 = (r == 0) ? 0u : (r == 1 ? t1 : (r == 2 ? t2 : t3));
    unsigned slot = gt0 * 16u + base[r] + loc;
    sstart[slot] = start;
    slen[slot] = len;
    slotof[b] = slot;  // b = r*NNODES + dst: exactly the lookup key k_node needs
  }
}

// ---- scatter src values into (rel,dst)-sorted edge order ----
__global__ void k_scat(const int* __restrict__ rel, const int* __restrict__ dst,
                       const int* __restrict__ src, const unsigned* __restrict__ cnt,
                       unsigned* __restrict__ cur, unsigned* __restrict__ ssrc) {
  int e = blockIdx.x * blockDim.x + threadIdx.x;
  if (e < NEDGES) {
    int r = rel[e]; r = r < 0 ? 0 : (r > NRELS - 1 ? NRELS - 1 : r);
    int key = r * NNODES + dst[e];
    unsigned pos = cnt[key] + atomicAdd(&cur[key], 1u);
    ssrc[pos] = (unsigned)src[e];
  }
}

// ---- group GEMM + per-group max -> PLAIN bf16 stores to gmax (no atomics) ----
// Strided tile assignment for load balance; B (W^T) register-resident, rel-uniform tiles.
__global__ __launch_bounds__(256, 2) void k_edge(
    const unsigned short* __restrict__ xbf, const unsigned short* __restrict__ Wt,
    const float* __restrict__ bias, const unsigned* __restrict__ ssrc,
    const unsigned* __restrict__ sstart, const unsigned* __restrict__ slen,
    const unsigned* __restrict__ ctrl, unsigned short* __restrict__ gmax) {
  int lane = threadIdx.x & 63;
  int wid = blockIdx.x * (blockDim.x >> 6) + (threadIdx.x >> 6);
  int nw = gridDim.x * (blockDim.x >> 6);
  int gt1 = (int)ctrl[9], gt2 = (int)ctrl[10], gt3 = (int)ctrl[11];
  int T = (int)ctrl[12];
  int col = lane & 15, quad = lane >> 4;
  bf16x8 B[8][4];
  float bs[8];
  int rcur = -1;

  for (int t = wid; t < T; t += nw) {
    int r = (t >= gt1) + (t >= gt2) + (t >= gt3);
    if (r != rcur) {
      rcur = r;
      const unsigned short* wr = Wt + (r << 14);
#pragma unroll
      for (int ct = 0; ct < 8; ct++) {
#pragma unroll
        for (int kk = 0; kk < 4; kk++)
          B[ct][kk] = *(const bf16x8*)(wr + ((ct * 16 + col) << 7) + kk * 32 + quad * 8);
        bs[ct] = bias[(r << 7) + ct * 16 + col];
      }
    }
    int sbase = t * 16;
    unsigned astart = sstart[sbase + col];   // this lane's A-row group
    int alen = (int)slen[sbase + col];
    int aclamp = alen > 0 ? alen - 1 : 0;
    f32x4 mx[8];
#pragma unroll
    for (int ct = 0; ct < 8; ct++) mx[ct] = (f32x4){-3.0e38f, -3.0e38f, -3.0e38f, -3.0e38f};

    int step = 0;
    unsigned sa = ssrc[astart];  // padding rows: slen=0, sstart=0 -> valid dummy
    while (__any(step < alen)) {
      const unsigned short* xr = xbf + ((size_t)sa << 7);
      bf16x8 a0 = *(const bf16x8*)(xr + quad * 8);
      bf16x8 a1 = *(const bf16x8*)(xr + 32 + quad * 8);
      bf16x8 a2 = *(const bf16x8*)(xr + 64 + quad * 8);
      bf16x8 a3 = *(const bf16x8*)(xr + 96 + quad * 8);
      sa = ssrc[astart + min(step + 1, aclamp)];  // prefetch next step's src id
#pragma unroll
      for (int ct = 0; ct < 8; ct++) {
        f32x4 acc = {0.f, 0.f, 0.f, 0.f};
        acc = __builtin_amdgcn_mfma_f32_16x16x32_bf16(a0, B[ct][0], acc, 0, 0, 0);
        acc = __builtin_amdgcn_mfma_f32_16x16x32_bf16(a1, B[ct][1], acc, 0, 0, 0);
        acc = __builtin_amdgcn_mfma_f32_16x16x32_bf16(a2, B[ct][2], acc, 0, 0, 0);
        acc = __builtin_amdgcn_mfma_f32_16x16x32_bf16(a3, B[ct][3], acc, 0, 0, 0);
#pragma unroll
        for (int j = 0; j < 4; j++) mx[ct][j] = fmaxf(mx[ct][j], acc[j]);
      }
      step++;
    }
    // plain stores: slot row = sbase + quad*4 + j (padding rows written, never read)
#pragma unroll
    for (int ct = 0; ct < 8; ct++) {
#pragma unroll
      for (int j = 0; j < 4; j++) {
        size_t idx = ((size_t)(sbase + quad * 4 + j) << 7) + (unsigned)(ct * 16 + col);
        gmax[idx] = f2bf(mx[ct][j] + bs[ct]);
      }
    }
  }
}

// ---- self-loop GEMM + fused cross-rel max reduce (<=4 slots/node) + store f32 ----
__global__ __launch_bounds__(256, 2) void k_node(
    const unsigned short* __restrict__ x, const unsigned short* __restrict__ Wt,
    const float* __restrict__ bias, const unsigned* __restrict__ slotof,
    const unsigned short* __restrict__ gmax, float* __restrict__ out) {
  int lane = threadIdx.x & 63;
  int wid = blockIdx.x * (blockDim.x >> 6) + (threadIdx.x >> 6);
  int col = lane & 15, quad = lane >> 4;
  int row0 = wid * 16;
  if (row0 >= NNODES) return;

  const unsigned short* wr = Wt + (4 << 14);
  bf16x8 B[8][4];
  float bs[8];
#pragma unroll
  for (int ct = 0; ct < 8; ct++) {
#pragma unroll
    for (int kk = 0; kk < 4; kk++)
      B[ct][kk] = *(const bf16x8*)(wr + ((ct * 16 + col) << 7) + kk * 32 + quad * 8);
    bs[ct] = bias[(4 << 7) + ct * 16 + col];
  }
  int na = min(row0 + col, NNODES - 1);
  bf16x8 a0 = *(const bf16x8*)(x + (na << 7) + quad * 8);
  bf16x8 a1 = *(const bf16x8*)(x + (na << 7) + 32 + quad * 8);
  bf16x8 a2 = *(const bf16x8*)(x + (na << 7) + 64 + quad * 8);
  bf16x8 a3 = *(const bf16x8*)(x + (na << 7) + 96 + quad * 8);

  // slot lookups for this lane's 4 C-rows x 4 rels (validity uniform across row's 16 lanes)
  unsigned sl[4][NRELS];
  bool anyv[4];
#pragma unroll
  for (int j = 0; j < 4; j++) {
    int n = row0 + quad * 4 + j;
    bool a = false;
#pragma unroll
    for (int r = 0; r < NRELS; r++) {
      unsigned s = slotof[r * NNODES + n];
      sl[j][r] = s;
      a |= (s != 0xFFFFFFFFu);
    }
    anyv[j] = a;
  }

#pragma unroll
  for (int ct = 0; ct < 8; ct++) {
    f32x4 acc = {0.f, 0.f, 0.f, 0.f};
    acc = __builtin_amdgcn_mfma_f32_16x16x32_bf16(a0, B[ct][0], acc, 0, 0, 0);
    acc = __builtin_amdgcn_mfma_f32_16x16x32_bf16(a1, B[ct][1], acc, 0, 0, 0);
    acc = __builtin_amdgcn_mfma_f32_16x16x32_bf16(a2, B[ct][2], acc, 0, 0, 0);
    acc = __builtin_amdgcn_mfma_f32_16x16x32_bf16(a3, B[ct][3], acc, 0, 0, 0);
#pragma unroll
    for (int j = 0; j < 4; j++) {
      int n = row0 + quad * 4 + j;
      float m = -3.0e38f;
#pragma unroll
      for (int r = 0; r < NRELS; r++) {
        unsigned s = sl[j][r];
        if (s != 0xFFFFFFFFu)
          m = fmaxf(m, bf2f(gmax[((size_t)s << 7) + (unsigned)(ct * 16 + col)]));
      }
      float av = anyv[j] ? m : 0.f;  // DGL zero-fill for nodes w/o in-edges
      out[((size_t)n << 7) + (unsigned)(ct * 16 + col)] = acc[j] + bs[ct] + av;
    }
  }
}

extern "C" void kernel_launch(void* const* d_in, const int* in_sizes, int n_in,
                              void* d_out, int out_size, void* d_ws, size_t ws_size,
                              hipStream_t stream) {
  const float* x = (const float*)d_in[0];
  const float* W = (const float*)d_in[1];
  const float* bias = (const float*)d_in[2];
  const int* src = (const int*)d_in[3];
  const int* dst = (const int*)d_in[4];
  const int* rel = (const int*)d_in[5];

  char* ws = (char*)d_ws;
  unsigned* ssrc = (unsigned*)(ws + SSRC_OFF);
  unsigned* cnt = (unsigned*)(ws + CNT_OFF);
  unsigned* bsum = (unsigned*)(ws + BSUM_OFF);
  unsigned* ctrl = (unsigned*)(ws + CTRL_OFF);
  unsigned* sstart = (unsigned*)(ws + SSTART_OFF);
  unsigned* slen = (unsigned*)(ws + SLEN_OFF);
  unsigned* cur = (unsigned*)(ws + CUR_OFF);
  unsigned* slotof = (unsigned*)(ws + SLOTOF_OFF);
  unsigned short* Wt = (unsigned short*)(ws + WT_OFF);
  unsigned short* xbf = (unsigned short*)(ws + XBF_OFF);
  unsigned short* gmax = (unsigned short*)(ws + GMAX_OFF);

  hipLaunchKernelGGL(k_init, dim3(1024), dim3(256), 0, stream, cnt, slotof);
  hipLaunchKernelGGL(k_convwt, dim3(3125), dim3(256), 0, stream, x, xbf, W, Wt);
  hipLaunchKernelGGL(k_hist, dim3(3125), dim3(256), 0, stream, rel, dst, cnt);
  hipLaunchKernelGGL(k_scanA, dim3(NBLKS), dim3(256), 0, stream, cnt, bsum);
  hipLaunchKernelGGL(k_scanC, dim3(NBLKS), dim3(256), 0, stream, cnt, bsum);
  hipLaunchKernelGGL(k_gcount, dim3(782), dim3(256), 0, stream, cnt, ctrl);
  hipLaunchKernelGGL(k_gfill, dim3(782), dim3(256), 0, stream, cnt, ctrl, sstart, slen, slotof);
  hipLaunchKernelGGL(k_scat, dim3(3125), dim3(256), 0, stream, rel, dst, src, cnt, cur, ssrc);
  hipLaunchKernelGGL(k_edge, dim3(1024), dim3(256), 0, stream, xbf, Wt, bias, ssrc, sstart, slen,
                     ctrl, gmax);
  hipLaunchKernelGGL(k_node, dim3(782), dim3(256), 0, stream, xbf, Wt, bias, slotof, gmax,
                     (float*)d_out);
}

// Round 6
// 344.972 us; speedup vs baseline: 7.6364x; 1.1141x over previous
//
#include <hip/hip_runtime.h>

// Problem constants (fixed by setup_inputs)
#define NNODES 50000
#define NEDGES 800000
#define DIM    128
#define NRELS  4               // edge relations; weight slice 4 = self-loop
#define NB     (NRELS*NNODES)  // 200000 (rel,dst) bins
#define NBLKS  98              // scan blocks: 98*2048 = 200704 >= NB+1
#define NSLOTS 200128          // max slots incl per-rel tile padding

typedef __attribute__((ext_vector_type(8))) short bf16x8;
typedef __attribute__((ext_vector_type(8))) unsigned short u16x8;
typedef __attribute__((ext_vector_type(4))) float f32x4;

// ---- ws layout (bytes) ----
#define SSRC_OFF   0            // u32[NEDGES+16]        3,200,064
#define CNT_OFF    3200256      // u32[200704]             802,816 (bins -> excl scan)
#define BSUM_OFF   4003072      // u32[128]
#define CTRL_OFF   4003584      // u32[64]: [8..12] tile offsets per rel
#define LHIST_OFF  4003840      // u32[256] (rel,lenb) histogram
#define LBASE_OFF  4004864      // u32[256] slot base per (rel,lenb) bin
#define GCUR_OFF   4005888      // u32[256] running cursor per bin
#define SSTART_OFF 4006912      // u32[NSLOTS]             800,512
#define SLEN_OFF   4807424      // u32[NSLOTS]             800,512
#define CUR_OFF    5607936      // u32[NB]                 800,256
#define SLOTOF_OFF 6408192      // u32[NB] (0xFFFFFFFF = empty)  800,256
#define WT_OFF     7208448      // bf16[5*128*128]         163,840
#define XBF_OFF    7372288      // bf16[NNODES*DIM]     12,800,000
#define GMAX_OFF   20172288     // bf16[NSLOTS*128]     51,232,768 -> total ~71.4 MB
#define NZERO      ((SLOTOF_OFF - CNT_OFF) / 4)  // 801,984 u32 zeroed

__device__ __forceinline__ unsigned short f2bf(float f) {  // RNE f32->bf16
  unsigned u = __float_as_uint(f);
  return (unsigned short)((u + 0x7FFFu + ((u >> 16) & 1u)) >> 16);
}
__device__ __forceinline__ float bf2f(unsigned short u) {
  return __uint_as_float(((unsigned)u) << 16);
}

// ---- prep: x f32->bf16, W transpose+convert, zero ctrl region, slotof=-1 ----
__global__ void k_prep(const float* __restrict__ x, unsigned short* __restrict__ xbf,
                       const float* __restrict__ W, unsigned short* __restrict__ Wt,
                       unsigned* __restrict__ z, unsigned* __restrict__ sf) {
  int i = blockIdx.x * blockDim.x + threadIdx.x;
  if (i < NNODES * DIM / 8) {
    const float4* p = (const float4*)x + i * 2;
    float4 v0 = p[0], v1 = p[1];
    u16x8 o;
    o[0] = f2bf(v0.x); o[1] = f2bf(v0.y); o[2] = f2bf(v0.z); o[3] = f2bf(v0.w);
    o[4] = f2bf(v1.x); o[5] = f2bf(v1.y); o[6] = f2bf(v1.z); o[7] = f2bf(v1.w);
    *(u16x8*)(xbf + i * 8) = o;
  }
  if (i < 5 * DIM * DIM) {
    int r = i >> 14, rem = i & 16383, k = rem >> 7, c = rem & 127;
    Wt[(r << 14) + (c << 7) + k] = f2bf(W[i]);
  }
  if (i < NZERO) z[i] = 0u;
  if (i < NB) sf[i] = 0xFFFFFFFFu;
}

// ---- histogram over (rel,dst) bins ----
__global__ void k_hist(const int* __restrict__ rel, const int* __restrict__ dst,
                       unsigned* __restrict__ cnt) {
  int e = blockIdx.x * blockDim.x + threadIdx.x;
  if (e < NEDGES) {
    int r = rel[e]; r = r < 0 ? 0 : (r > NRELS - 1 ? NRELS - 1 : r);
    atomicAdd(&cnt[r * NNODES + dst[e]], 1u);
  }
}

// ---- block-local exclusive scan over cnt (2048/block), in place ----
__global__ void k_scanA(unsigned* __restrict__ cnt, unsigned* __restrict__ bsum) {
  __shared__ unsigned sh[256];
  int tid = threadIdx.x;
  int base = blockIdx.x * 2048 + tid * 8;
  unsigned v[8], tsum = 0;
#pragma unroll
  for (int j = 0; j < 8; j++) { v[j] = cnt[base + j]; tsum += v[j]; }
  sh[tid] = tsum;
  __syncthreads();
  for (int off = 1; off < 256; off <<= 1) {
    unsigned t = (tid >= off) ? sh[tid - off] : 0u;
    __syncthreads();
    sh[tid] += t;
    __syncthreads();
  }
  unsigned run = sh[tid] - tsum;
#pragma unroll
  for (int j = 0; j < 8; j++) { unsigned t = v[j]; cnt[base + j] = run; run += t; }
  if (tid == 255) bsum[blockIdx.x] = sh[255];
}

// ---- add block-prefix ----
__global__ void k_scanC(unsigned* __restrict__ cnt, const unsigned* __restrict__ bsum) {
  int blk = blockIdx.x;
  if (blk == 0) return;
  unsigned p = 0;
  for (int k = 0; k < blk; k++) p += bsum[k];
  int base = blk * 2048 + threadIdx.x * 8;
#pragma unroll
  for (int j = 0; j < 8; j++) cnt[base + j] += p;
}

// ---- histogram of group lengths into 256 (rel,lenb) bins ----
__global__ void k_lhist(const unsigned* __restrict__ cnt, unsigned* __restrict__ lhist) {
  __shared__ unsigned h[256];
  h[threadIdx.x] = 0u;
  __syncthreads();
  int b = blockIdx.x * blockDim.x + threadIdx.x;
  if (b < NB) {
    unsigned len = cnt[b + 1] - cnt[b];
    if (len) {
      int r = b / NNODES;
      int bin = (r << 6) + (int)min(len, 63u);
      atomicAdd(&h[bin], 1u);
    }
  }
  __syncthreads();
  if (h[threadIdx.x]) atomicAdd(&lhist[threadIdx.x], h[threadIdx.x]);
}

// ---- single-block scan of 256 bins -> per-bin slot base + per-rel tile offsets ----
// Slots within a rel are ordered by length bucket => tiles have near-uniform group len.
__global__ void k_lscan(const unsigned* __restrict__ lhist, unsigned* __restrict__ lbase,
                        unsigned* __restrict__ ctrl) {
  __shared__ unsigned sh[256];
  __shared__ unsigned pbs[NRELS], rex[NRELS];
  int tid = threadIdx.x;
  unsigned v = lhist[tid];
  sh[tid] = v;
  __syncthreads();
  for (int off = 1; off < 256; off <<= 1) {
    unsigned t = (tid >= off) ? sh[tid - off] : 0u;
    __syncthreads();
    sh[tid] += t;
    __syncthreads();
  }
  unsigned ex = sh[tid] - v;  // exclusive prefix
  if (tid == 0) {
    unsigned tt = 0;
    ctrl[8] = 0;
    for (int r = 0; r < NRELS; r++) {
      unsigned hi = sh[r * 64 + 63];
      unsigned lo = (r == 0) ? 0u : sh[r * 64 - 1];
      rex[r] = lo;
      pbs[r] = tt * 16u;               // slot base of rel region (16-aligned)
      tt += (hi - lo + 15u) / 16u;     // tiles for this rel
      ctrl[9 + r] = tt;
    }
  }
  __syncthreads();
  lbase[tid] = pbs[tid >> 6] + (ex - rex[tid >> 6]);
}

// ---- ranked fill: slot = lbase[bin] + block-base + LDS-local rank ----
__global__ void k_gfill(const unsigned* __restrict__ cnt, const unsigned* __restrict__ lbase,
                        unsigned* __restrict__ gcur, unsigned* __restrict__ sstart,
                        unsigned* __restrict__ slen, unsigned* __restrict__ slotof) {
  __shared__ unsigned h[256], basearr[256];
  h[threadIdx.x] = 0u;
  __syncthreads();
  int b = blockIdx.x * blockDim.x + threadIdx.x;
  unsigned start = 0, len = 0, loc = 0;
  int bin = 0;
  if (b < NB) {
    start = cnt[b];
    len = cnt[b + 1] - start;
    if (len) {
      int r = b / NNODES;
      bin = (r << 6) + (int)min(len, 63u);
      loc = atomicAdd(&h[bin], 1u);
    }
  }
  __syncthreads();
  unsigned hv = h[threadIdx.x];
  basearr[threadIdx.x] = hv ? atomicAdd(&gcur[threadIdx.x], hv) : 0u;
  __syncthreads();
  if (len) {
    unsigned slot = lbase[bin] + basearr[bin] + loc;
    sstart[slot] = start;
    slen[slot] = len;
    slotof[b] = slot;  // b = r*NNODES + dst: the lookup key k_node needs
  }
}

// ---- scatter src values into (rel,dst)-sorted edge order ----
__global__ void k_scat(const int* __restrict__ rel, const int* __restrict__ dst,
                       const int* __restrict__ src, const unsigned* __restrict__ cnt,
                       unsigned* __restrict__ cur, unsigned* __restrict__ ssrc) {
  int e = blockIdx.x * blockDim.x + threadIdx.x;
  if (e < NEDGES) {
    int r = rel[e]; r = r < 0 ? 0 : (r > NRELS - 1 ? NRELS - 1 : r);
    int key = r * NNODES + dst[e];
    unsigned pos = cnt[key] + atomicAdd(&cur[key], 1u);
    ssrc[pos] = (unsigned)src[e];
  }
}

// ---- group GEMM + per-group max -> plain bf16 stores to gmax ----
// Length-sorted slots => uniform steps per tile; strided tile assignment.
__global__ __launch_bounds__(256, 2) void k_edge(
    const unsigned short* __restrict__ xbf, const unsigned short* __restrict__ Wt,
    const float* __restrict__ bias, const unsigned* __restrict__ ssrc,
    const unsigned* __restrict__ sstart, const unsigned* __restrict__ slen,
    const unsigned* __restrict__ ctrl, unsigned short* __restrict__ gmax) {
  int lane = threadIdx.x & 63;
  int wid = blockIdx.x * (blockDim.x >> 6) + (threadIdx.x >> 6);
  int nw = gridDim.x * (blockDim.x >> 6);
  int gt1 = (int)ctrl[9], gt2 = (int)ctrl[10], gt3 = (int)ctrl[11];
  int T = (int)ctrl[12];
  int col = lane & 15, quad = lane >> 4;
  bf16x8 B[8][4];
  float bs[8];
  int rcur = -1;

  for (int t = wid; t < T; t += nw) {
    int r = (t >= gt1) + (t >= gt2) + (t >= gt3);
    if (r != rcur) {
      rcur = r;
      const unsigned short* wr = Wt + (r << 14);
#pragma unroll
      for (int ct = 0; ct < 8; ct++) {
#pragma unroll
        for (int kk = 0; kk < 4; kk++)
          B[ct][kk] = *(const bf16x8*)(wr + ((ct * 16 + col) << 7) + kk * 32 + quad * 8);
        bs[ct] = bias[(r << 7) + ct * 16 + col];
      }
    }
    int sbase = t * 16;
    unsigned astart = sstart[sbase + col];   // this lane's A-row group
    int alen = (int)slen[sbase + col];
    int aclamp = alen > 0 ? alen - 1 : 0;
    f32x4 mx[8];
#pragma unroll
    for (int ct = 0; ct < 8; ct++) mx[ct] = (f32x4){-3.0e38f, -3.0e38f, -3.0e38f, -3.0e38f};

    int step = 0;
    unsigned sa = ssrc[astart];  // padding rows: slen=0, sstart=0 -> valid dummy
    while (__any(step < alen)) {
      const unsigned short* xr = xbf + ((size_t)sa << 7);
      bf16x8 a0 = *(const bf16x8*)(xr + quad * 8);
      bf16x8 a1 = *(const bf16x8*)(xr + 32 + quad * 8);
      bf16x8 a2 = *(const bf16x8*)(xr + 64 + quad * 8);
      bf16x8 a3 = *(const bf16x8*)(xr + 96 + quad * 8);
      sa = ssrc[astart + min(step + 1, aclamp)];  // prefetch next step's src id
#pragma unroll
      for (int ct = 0; ct < 8; ct++) {
        f32x4 acc = {0.f, 0.f, 0.f, 0.f};
        acc = __builtin_amdgcn_mfma_f32_16x16x32_bf16(a0, B[ct][0], acc, 0, 0, 0);
        acc = __builtin_amdgcn_mfma_f32_16x16x32_bf16(a1, B[ct][1], acc, 0, 0, 0);
        acc = __builtin_amdgcn_mfma_f32_16x16x32_bf16(a2, B[ct][2], acc, 0, 0, 0);
        acc = __builtin_amdgcn_mfma_f32_16x16x32_bf16(a3, B[ct][3], acc, 0, 0, 0);
#pragma unroll
        for (int j = 0; j < 4; j++) mx[ct][j] = fmaxf(mx[ct][j], acc[j]);
      }
      step++;
    }
#pragma unroll
    for (int ct = 0; ct < 8; ct++) {
#pragma unroll
      for (int j = 0; j < 4; j++) {
        size_t idx = ((size_t)(sbase + quad * 4 + j) << 7) + (unsigned)(ct * 16 + col);
        gmax[idx] = f2bf(mx[ct][j] + bs[ct]);
      }
    }
  }
}

// ---- self-loop GEMM + fused cross-rel max reduce (<=4 slots/node) + store f32 ----
__global__ __launch_bounds__(256, 2) void k_node(
    const unsigned short* __restrict__ x, const unsigned short* __restrict__ Wt,
    const float* __restrict__ bias, const unsigned* __restrict__ slotof,
    const unsigned short* __restrict__ gmax, float* __restrict__ out) {
  int lane = threadIdx.x & 63;
  int wid = blockIdx.x * (blockDim.x >> 6) + (threadIdx.x >> 6);
  int col = lane & 15, quad = lane >> 4;
  int row0 = wid * 16;
  if (row0 >= NNODES) return;

  const unsigned short* wr = Wt + (4 << 14);
  bf16x8 B[8][4];
  float bs[8];
#pragma unroll
  for (int ct = 0; ct < 8; ct++) {
#pragma unroll
    for (int kk = 0; kk < 4; kk++)
      B[ct][kk] = *(const bf16x8*)(wr + ((ct * 16 + col) << 7) + kk * 32 + quad * 8);
    bs[ct] = bias[(4 << 7) + ct * 16 + col];
  }
  int na = min(row0 + col, NNODES - 1);
  bf16x8 a0 = *(const bf16x8*)(x + (na << 7) + quad * 8);
  bf16x8 a1 = *(const bf16x8*)(x + (na << 7) + 32 + quad * 8);
  bf16x8 a2 = *(const bf16x8*)(x + (na << 7) + 64 + quad * 8);
  bf16x8 a3 = *(const bf16x8*)(x + (na << 7) + 96 + quad * 8);

  unsigned sl[4][NRELS];
  bool anyv[4];
#pragma unroll
  for (int j = 0; j < 4; j++) {
    int n = row0 + quad * 4 + j;
    bool a = false;
#pragma unroll
    for (int r = 0; r < NRELS; r++) {
      unsigned s = slotof[r * NNODES + n];
      sl[j][r] = s;
      a |= (s != 0xFFFFFFFFu);
    }
    anyv[j] = a;
  }

#pragma unroll
  for (int ct = 0; ct < 8; ct++) {
    f32x4 acc = {0.f, 0.f, 0.f, 0.f};
    acc = __builtin_amdgcn_mfma_f32_16x16x32_bf16(a0, B[ct][0], acc, 0, 0, 0);
    acc = __builtin_amdgcn_mfma_f32_16x16x32_bf16(a1, B[ct][1], acc, 0, 0, 0);
    acc = __builtin_amdgcn_mfma_f32_16x16x32_bf16(a2, B[ct][2], acc, 0, 0, 0);
    acc = __builtin_amdgcn_mfma_f32_16x16x32_bf16(a3, B[ct][3], acc, 0, 0, 0);
#pragma unroll
    for (int j = 0; j < 4; j++) {
      int n = row0 + quad * 4 + j;
      float m = -3.0e38f;
#pragma unroll
      for (int r = 0; r < NRELS; r++) {
        unsigned s = sl[j][r];
        if (s != 0xFFFFFFFFu)
          m = fmaxf(m, bf2f(gmax[((size_t)s << 7) + (unsigned)(ct * 16 + col)]));
      }
      float av = anyv[j] ? m : 0.f;  // DGL zero-fill for nodes w/o in-edges
      out[((size_t)n << 7) + (unsigned)(ct * 16 + col)] = acc[j] + bs[ct] + av;
    }
  }
}

extern "C" void kernel_launch(void* const* d_in, const int* in_sizes, int n_in,
                              void* d_out, int out_size, void* d_ws, size_t ws_size,
                              hipStream_t stream) {
  const float* x = (const float*)d_in[0];
  const float* W = (const float*)d_in[1];
  const float* bias = (const float*)d_in[2];
  const int* src = (const int*)d_in[3];
  const int* dst = (const int*)d_in[4];
  const int* rel = (const int*)d_in[5];

  char* ws = (char*)d_ws;
  unsigned* ssrc = (unsigned*)(ws + SSRC_OFF);
  unsigned* cnt = (unsigned*)(ws + CNT_OFF);
  unsigned* bsum = (unsigned*)(ws + BSUM_OFF);
  unsigned* ctrl = (unsigned*)(ws + CTRL_OFF);
  unsigned* lhist = (unsigned*)(ws + LHIST_OFF);
  unsigned* lbase = (unsigned*)(ws + LBASE_OFF);
  unsigned* gcur = (unsigned*)(ws + GCUR_OFF);
  unsigned* sstart = (unsigned*)(ws + SSTART_OFF);
  unsigned* slen = (unsigned*)(ws + SLEN_OFF);
  unsigned* cur = (unsigned*)(ws + CUR_OFF);
  unsigned* slotof = (unsigned*)(ws + SLOTOF_OFF);
  unsigned short* Wt = (unsigned short*)(ws + WT_OFF);
  unsigned short* xbf = (unsigned short*)(ws + XBF_OFF);
  unsigned short* gmax = (unsigned short*)(ws + GMAX_OFF);

  hipLaunchKernelGGL(k_prep, dim3(3133), dim3(256), 0, stream, x, xbf, W, Wt, cnt, slotof);
  hipLaunchKernelGGL(k_hist, dim3(3125), dim3(256), 0, stream, rel, dst, cnt);
  hipLaunchKernelGGL(k_scanA, dim3(NBLKS), dim3(256), 0, stream, cnt, bsum);
  hipLaunchKernelGGL(k_scanC, dim3(NBLKS), dim3(256), 0, stream, cnt, bsum);
  hipLaunchKernelGGL(k_lhist, dim3(782), dim3(256), 0, stream, cnt, lhist);
  hipLaunchKernelGGL(k_lscan, dim3(1), dim3(256), 0, stream, lhist, lbase, ctrl);
  hipLaunchKernelGGL(k_gfill, dim3(782), dim3(256), 0, stream, cnt, lbase, gcur, sstart, slen,
                     slotof);
  hipLaunchKernelGGL(k_scat, dim3(3125), dim3(256), 0, stream, rel, dst, src, cnt, cur, ssrc);
  hipLaunchKernelGGL(k_edge, dim3(2048), dim3(256), 0, stream, xbf, Wt, bias, ssrc, sstart, slen,
                     ctrl, gmax);
  hipLaunchKernelGGL(k_node, dim3(782), dim3(256), 0, stream, xbf, Wt, bias, slotof, gmax,
                     (float*)d_out);
}